// Round 3
// baseline (29206.055 us; speedup 1.0000x reference)
//
#include <hip/hip_runtime.h>
#include <stddef.h>

// BiLSTM-CRF fused implementation, round 3.
// Round-2 diff: (1) FIX bsum race in k_gxall (barrier after bias write);
// (2) k_sent h ping-pong stores are agent-scope atomics (cross-XCD visibility).

__device__ __forceinline__ float sigm(float x){ return 1.0f/(1.0f + expf(-x)); }

// ---------------------------------------------------------------------------
// fv[b*S+s][j] = feat_b[j] + sum_f features[b][f][s] * feat_W[j][f]
__global__ __launch_bounds__(256) void k_fv(const float* __restrict__ feat,
                                            const float* __restrict__ fW,
                                            const float* __restrict__ fb,
                                            float* __restrict__ fvb)
{
  int idx = blockIdx.x*256 + threadIdx.x;
  int j = idx & 127;
  int r = idx >> 7;
  int b = r >> 7, sw = r & 127;
  const float* x = feat + b*512 + sw;
  float a = fb[j];
  a = fmaf(x[0],   fW[j*4+0], a);
  a = fmaf(x[128], fW[j*4+1], a);
  a = fmaf(x[256], fW[j*4+2], a);
  a = fmaf(x[384], fW[j*4+3], a);
  fvb[idx] = a;
}

// ---------------------------------------------------------------------------
// tab[d][c][gi] = bih[orig]+bhh[orig] + dot(Wih[orig], char_emb[c])   (gi unit-major)
__global__ __launch_bounds__(256) void k_gxc(
  const float* __restrict__ char_emb,
  const float* __restrict__ Wih_f, const float* __restrict__ bih_f, const float* __restrict__ bhh_f,
  const float* __restrict__ Wih_b, const float* __restrict__ bih_b, const float* __restrict__ bhh_b,
  float* __restrict__ tab)
{
  int idx = blockIdx.x*256 + threadIdx.x;   // 2*500*256
  int gi = idx & 255;
  int c  = (idx >> 8) % 500;
  int d  = idx / (500*256);
  const float* Wih = d ? Wih_b : Wih_f;
  int orig = (gi&3)*64 + (gi>>2);
  const float* w = Wih + orig*64;
  const float* e = char_emb + c*64;
  float a = (d?bih_b:bih_f)[orig] + (d?bhh_b:bhh_f)[orig];
  #pragma unroll 8
  for (int k=0;k<64;k++) a = fmaf(w[k], e[k], a);
  tab[idx] = a;
}

// ---------------------------------------------------------------------------
// All 16 char-LSTM steps in one kernel. WG = (dir, 32 seqs), grid 1024x256.
__global__ __launch_bounds__(256) void k_char(
  const int* __restrict__ chars2ix,
  const float* __restrict__ Whh_f, const float* __restrict__ Whh_b,
  const float* __restrict__ tab, float* __restrict__ chh)
{
  __shared__ __align__(16) float Wl[256*64];   // 64 KB swizzled
  __shared__ __align__(16) float hbuf[4][8][64]; // 8 KB
  __shared__ float gbuf[4][64][4];             // 4 KB
  int tid = threadIdx.x, bid = blockIdx.x;
  int dir = bid >> 9, chunk = bid & 511;
  const float* Whh = dir ? Whh_b : Whh_f;
  for (int i = tid; i < 256*16; i += 256) {
    int g = i >> 4, k4 = i & 15;
    int orig = (g&3)*64 + (g>>2);
    *(float4*)&Wl[(g*64 + k4*4) ^ ((g&7)<<2)] = *(const float4*)(Whh + orig*64 + k4*4);
  }
  for (int i = tid; i < 4*8*64; i += 256) ((float*)hbuf)[i] = 0.f;
  __syncthreads();
  int wave = __builtin_amdgcn_readfirstlane((int)(tid>>6));
  int l = tid & 63;
  int seq0 = chunk*32 + wave*8;
  float cs[4][2];
  #pragma unroll
  for (int gt=0;gt<4;gt++){ cs[gt][0]=0.f; cs[gt][1]=0.f; }
  const float* tb = tab + dir*500*256;
  int ul = l & 15, ss = l >> 4;

  for (int t=0;t<16;t++){
    int tpos = dir ? 15-t : t;
    int cid[8];
    #pragma unroll
    for (int i=0;i<8;i++) cid[i] = chars2ix[(seq0+i)*16 + tpos];
    float acc[4][8];
    // all dots first (reads h(t)), then all activations (writes h(t+1))
    #pragma unroll
    for (int gt=0; gt<4; gt++){
      #pragma unroll
      for (int i=0;i<8;i++) acc[gt][i] = tb[cid[i]*256 + gt*64 + l];
      int g = gt*64 + l;
      #pragma unroll
      for (int k4=0;k4<16;k4++){
        float4 w = *(const float4*)&Wl[(g*64 + k4*4) ^ ((g&7)<<2)];
        #pragma unroll
        for (int i=0;i<8;i++){
          const float4 x = *(const float4*)&hbuf[wave][i][k4*4];
          acc[gt][i] = fmaf(x.x,w.x, fmaf(x.y,w.y, fmaf(x.z,w.z, fmaf(x.w,w.w, acc[gt][i]))));
        }
      }
    }
    #pragma unroll
    for (int gt=0; gt<4; gt++){
      int u = gt*16 + ul;
      #pragma unroll
      for (int half=0; half<2; half++){
        #pragma unroll
        for (int i=0;i<4;i++) gbuf[wave][l][i] = acc[gt][half*4+i];
        // same-wave exchange: ordered by lgkmcnt, no barrier
        float g_i = gbuf[wave][ul*4+0][ss];
        float g_f = gbuf[wave][ul*4+1][ss];
        float g_g = gbuf[wave][ul*4+2][ss];
        float g_o = gbuf[wave][ul*4+3][ss];
        float cc = cs[gt][half];
        cc = sigm(g_f)*cc + sigm(g_i)*tanhf(g_g);
        cs[gt][half] = cc;
        hbuf[wave][half*4+ss][u] = sigm(g_o)*tanhf(cc);
      }
    }
  }
  #pragma unroll
  for (int i=0;i<8;i++)
    chh[(size_t)(dir*16384 + seq0 + i)*64 + l] = hbuf[wave][i][l];
}

// ---------------------------------------------------------------------------
// chvec[r][j] = b2[j] + [hf|hb] @ W2[j]
__global__ __launch_bounds__(256) void k_chvec(
  const float* __restrict__ chh,
  const float* __restrict__ W2, const float* __restrict__ b2,
  float* __restrict__ chvec)
{
  __shared__ __align__(16) float Wc[64*128];
  __shared__ __align__(16) float gout[4][8][64];
  int tid = threadIdx.x, bid = blockIdx.x;
  for (int i=tid;i<64*32;i+=256){
    int l2=i>>5, k4=i&31;
    *(float4*)&Wc[(l2*128 + k4*4) ^ ((l2&7)<<2)] = *(const float4*)(W2 + l2*128 + k4*4);
  }
  __syncthreads();
  int wave = __builtin_amdgcn_readfirstlane((int)(tid>>6));
  int l = tid & 63;
  float bb = b2[l];
  for (int it=0; it<2; ++it){
    int r0 = bid*64 + it*32 + wave*8;
    float acc[8];
    #pragma unroll
    for (int i=0;i<8;i++) acc[i]=bb;
    const float* hf[8]; const float* hb[8];
    #pragma unroll
    for (int i=0;i<8;i++){ hf[i]=chh+(size_t)(r0+i)*64; hb[i]=chh+(size_t)(16384+r0+i)*64; }
    #pragma unroll
    for (int k4=0;k4<16;k4++){
      float4 w=*(const float4*)&Wc[(l*128+k4*4)^((l&7)<<2)];
      #pragma unroll
      for (int i=0;i<8;i++){
        const float4 x=*(const float4*)(hf[i]+k4*4);
        acc[i]=fmaf(x.x,w.x,fmaf(x.y,w.y,fmaf(x.z,w.z,fmaf(x.w,w.w,acc[i]))));
      }
    }
    #pragma unroll
    for (int k4=0;k4<16;k4++){
      float4 w=*(const float4*)&Wc[(l*128+64+k4*4)^((l&7)<<2)];
      #pragma unroll
      for (int i=0;i<8;i++){
        const float4 x=*(const float4*)(hb[i]+k4*4);
        acc[i]=fmaf(x.x,w.x,fmaf(x.y,w.y,fmaf(x.z,w.z,fmaf(x.w,w.w,acc[i]))));
      }
    }
    #pragma unroll
    for (int i=0;i<8;i++) gout[wave][i][l]=acc[i];
    int rsub=l>>3, cg=l&7;
    #pragma unroll
    for (int i2=0;i2<2;i2++){
      int col=cg*8+i2*4;
      *(float4*)&chvec[(size_t)(r0+rsub)*64+col] = *(const float4*)&gout[wave][rsub][col];
    }
  }
}

// ---------------------------------------------------------------------------
// Fused input GEMM: gx[dir][s*128+b][gi] = bias + vec(we|chvec|fv) @ Wih^T
// grid 2048 = ct(16) x dir(2) x rch(64); 256 rows/WG; K=320 staged in 2 phases.
__global__ __launch_bounds__(256) void k_gxall(
  const int* __restrict__ words2ix, const float* __restrict__ word_emb,
  const float* __restrict__ chvec, const float* __restrict__ fvb,
  const float* __restrict__ Wih_f, const float* __restrict__ bih_f, const float* __restrict__ bhh_f,
  const float* __restrict__ Wih_b, const float* __restrict__ bih_b, const float* __restrict__ bhh_b,
  float* __restrict__ gxf, float* __restrict__ gxb)
{
  __shared__ __align__(16) float Wg[64*160];   // 40 KB per phase
  __shared__ float bsum[64];
  __shared__ __align__(16) float gout[4][8][64];
  int tid=threadIdx.x, bid=blockIdx.x;
  int ct = bid & 15, dir = (bid>>4)&1, rch = bid>>5;
  const float* Wih = dir ? Wih_b : Wih_f;
  float* gx = dir ? gxb : gxf;
  if (tid<64){
    int gi = ct*64 + tid, orig = (gi&3)*256 + (gi>>2);
    bsum[tid] = (dir?bih_b:bih_f)[orig] + (dir?bhh_b:bhh_f)[orig];
  }
  __syncthreads();   // FIX (round-2 race): bsum must be visible before any wave reads it
  int wave = __builtin_amdgcn_readfirstlane((int)(tid>>6));
  int l = tid & 63;
  for (int it=0; it<8; ++it){
    int r0 = rch*256 + it*32 + wave*8;
    float acc[8];
    const float *wp[8], *cp[8], *fp[8];
    #pragma unroll
    for (int i=0;i<8;i++){
      int r=r0+i; int b=r&127, sw=r>>7; int rid=b*128+sw;
      wp[i] = word_emb + (size_t)words2ix[rid]*128;
      cp[i] = chvec + (size_t)rid*64;
      fp[i] = fvb + (size_t)rid*128;
    }
    {
      float bb = bsum[l];
      #pragma unroll
      for (int i=0;i<8;i++) acc[i]=bb;
    }
    // phase A: K 0..159 (we 0..127, chvec 0..31)
    __syncthreads();
    for (int i=tid; i<64*40; i+=256){
      int g = i/40, k4 = i%40;
      int gi = ct*64+g, orig = (gi&3)*256 + (gi>>2);
      *(float4*)&Wg[(g*160 + k4*4) ^ ((g&7)<<2)] = *(const float4*)(Wih + orig*320 + k4*4);
    }
    __syncthreads();
    #pragma unroll
    for (int k4=0;k4<32;k4++){
      float4 w=*(const float4*)&Wg[(l*160 + k4*4) ^ ((l&7)<<2)];
      #pragma unroll
      for (int i=0;i<8;i++){
        const float4 x=*(const float4*)(wp[i]+k4*4);
        acc[i]=fmaf(x.x,w.x,fmaf(x.y,w.y,fmaf(x.z,w.z,fmaf(x.w,w.w,acc[i]))));
      }
    }
    #pragma unroll
    for (int k4=32;k4<40;k4++){
      float4 w=*(const float4*)&Wg[(l*160 + k4*4) ^ ((l&7)<<2)];
      #pragma unroll
      for (int i=0;i<8;i++){
        const float4 x=*(const float4*)(cp[i]+(k4-32)*4);
        acc[i]=fmaf(x.x,w.x,fmaf(x.y,w.y,fmaf(x.z,w.z,fmaf(x.w,w.w,acc[i]))));
      }
    }
    // phase B: K 160..319 (chvec 32..63, fv 0..127)
    __syncthreads();
    for (int i=tid; i<64*40; i+=256){
      int g = i/40, k4 = i%40;
      int gi = ct*64+g, orig = (gi&3)*256 + (gi>>2);
      *(float4*)&Wg[(g*160 + k4*4) ^ ((g&7)<<2)] = *(const float4*)(Wih + orig*320 + 160 + k4*4);
    }
    __syncthreads();
    #pragma unroll
    for (int k4=0;k4<8;k4++){
      float4 w=*(const float4*)&Wg[(l*160 + k4*4) ^ ((l&7)<<2)];
      #pragma unroll
      for (int i=0;i<8;i++){
        const float4 x=*(const float4*)(cp[i]+32+k4*4);
        acc[i]=fmaf(x.x,w.x,fmaf(x.y,w.y,fmaf(x.z,w.z,fmaf(x.w,w.w,acc[i]))));
      }
    }
    #pragma unroll
    for (int k4=8;k4<40;k4++){
      float4 w=*(const float4*)&Wg[(l*160 + k4*4) ^ ((l&7)<<2)];
      #pragma unroll
      for (int i=0;i<8;i++){
        const float4 x=*(const float4*)(fp[i]+(k4-8)*4);
        acc[i]=fmaf(x.x,w.x,fmaf(x.y,w.y,fmaf(x.z,w.z,fmaf(x.w,w.w,acc[i]))));
      }
    }
    #pragma unroll
    for (int i=0;i<8;i++) gout[wave][i][l]=acc[i];
    int rsub=l>>3, cg=l&7;
    #pragma unroll
    for (int i2=0;i2<2;i2++){
      int col=cg*8+i2*4;
      *(float4*)&gx[(size_t)(r0+rsub)*1024 + ct*64 + col] = *(const float4*)&gout[wave][rsub][col];
    }
  }
}

// ---------------------------------------------------------------------------
// Persistent sentence BiLSTM. grid 256x256 (1 WG/CU guaranteed via 140 KB LDS).
// bid: gt=bid&7 (128-gate tile), dir=(bid>>3)&1, chunk=bid>>4 (8 batch rows).
// Group = 8 WGs sharing (dir,chunk); per-step monotonic atomic barrier.
// h ping-pong in global via agent-scope atomics (cross-XCD coherent); c in regs.
__global__ __launch_bounds__(256) void k_sent(
  const float* __restrict__ gxf, const float* __restrict__ gxb,
  const float* __restrict__ Whh_f, const float* __restrict__ Whh_b,
  float* __restrict__ hA, float* __restrict__ hB,
  float* __restrict__ hsf, float* __restrict__ hsb,
  unsigned int* __restrict__ cnt)
{
  __shared__ __align__(16) float Wl[128*256];   // 128 KB
  __shared__ __align__(16) float hstage[8][256];// 8 KB
  __shared__ float gbuf[4][64][4];              // 4 KB
  int tid=threadIdx.x, bid=blockIdx.x;
  int gt = bid & 7, dir = (bid>>3)&1, chunk = bid>>4;
  int grp = bid >> 3;    // 0..31
  const float* Whh = dir ? Whh_b : Whh_f;
  const float* gx  = dir ? gxb : gxf;
  float* hs = dir ? hsb : hsf;
  int b0 = chunk*8;
  for (int i=tid; i<128*64; i+=256){
    int g = i>>6, k4 = i&63;
    int gi = gt*128 + g, orig = (gi&3)*256 + (gi>>2);
    *(float4*)&Wl[(g*256 + k4*4) ^ ((g&7)<<2)] = *(const float4*)(Whh + orig*256 + k4*4);
  }
  for (int i=tid; i<2048; i+=256) ((float*)hstage)[i] = 0.f;
  __syncthreads();
  int wave = __builtin_amdgcn_readfirstlane((int)(tid>>6));
  int l = tid & 63;
  int gsl = wave >> 1, rg = wave & 1;
  int grow = gsl*64 + l;                 // gate row within 128-tile
  int ul = l & 15, rsel = l >> 4;
  int au = gt*32 + gsl*16 + ul;          // output unit
  int ar = rg*4 + rsel;                  // row within chunk
  float creg = 0.f;
  float nxt[4];
  {
    int spos0 = dir ? 127 : 0;
    #pragma unroll
    for (int i=0;i<4;i++)
      nxt[i] = gx[(size_t)(spos0*128 + b0 + rg*4 + i)*1024 + gt*128 + grow];
  }
  for (int t=0; t<128; ++t){
    int spos = dir ? 127 - t : t;
    float acc[4];
    #pragma unroll
    for (int i=0;i<4;i++) acc[i] = nxt[i];
    #pragma unroll
    for (int k4=0;k4<64;k4++){
      float4 w = *(const float4*)&Wl[(grow*256 + k4*4) ^ ((grow&7)<<2)];
      #pragma unroll
      for (int i=0;i<4;i++){
        const float4 x = *(const float4*)&hstage[rg*4 + i][k4*4];
        acc[i] = fmaf(x.x,w.x, fmaf(x.y,w.y, fmaf(x.z,w.z, fmaf(x.w,w.w, acc[i]))));
      }
    }
    if (t < 127){
      int sposn = dir ? 126 - t : t+1;
      #pragma unroll
      for (int i=0;i<4;i++)
        nxt[i] = gx[(size_t)(sposn*128 + b0 + rg*4 + i)*1024 + gt*128 + grow];
    }
    #pragma unroll
    for (int i=0;i<4;i++) gbuf[wave][l][i] = acc[i];
    // same-wave exchange
    float g_i = gbuf[wave][ul*4+0][rsel];
    float g_f = gbuf[wave][ul*4+1][rsel];
    float g_g = gbuf[wave][ul*4+2][rsel];
    float g_o = gbuf[wave][ul*4+3][rsel];
    creg = sigm(g_f)*creg + sigm(g_i)*tanhf(g_g);
    float h = sigm(g_o)*tanhf(creg);
    float* hn = ((t&1)==0) ? hB : hA;   // h(t+1) -> buf[(t+1)&1]
    __hip_atomic_store(&hn[(size_t)(dir*128 + b0 + ar)*256 + au], h,
                       __ATOMIC_RELAXED, __HIP_MEMORY_SCOPE_AGENT);
    hs[(size_t)(spos*128 + b0 + ar)*256 + au] = h;
    __threadfence();
    __syncthreads();
    if (tid==0){
      atomicAdd(&cnt[grp], 1u);
      unsigned int target = 8u*(unsigned)(t+1);
      while (__hip_atomic_load(&cnt[grp], __ATOMIC_ACQUIRE, __HIP_MEMORY_SCOPE_AGENT) < target) {}
    }
    __syncthreads();
    if (t < 127){
      const float* hc = ((t&1)==0) ? hB : hA;
      #pragma unroll
      for (int i=0;i<8;i++){
        unsigned int v = __hip_atomic_load(
          (const unsigned int*)&hc[(size_t)(dir*128 + b0 + i)*256 + tid],
          __ATOMIC_RELAXED, __HIP_MEMORY_SCOPE_AGENT);
        hstage[i][tid] = __uint_as_float(v);
      }
      __syncthreads();
    }
  }
}

// ---------------------------------------------------------------------------
// feats[b*128+s][k] = tag_b[k] + [hsf|hsb|chvec|fv] . tag_W[k]  (K=704, 2 passes)
__global__ __launch_bounds__(256) void k_feats(
  const float* __restrict__ hsf, const float* __restrict__ hsb,
  const float* __restrict__ chvec, const float* __restrict__ fvb,
  const float* __restrict__ tagW, const float* __restrict__ tagb,
  float* __restrict__ feats)
{
  __shared__ __align__(16) float Wt[27*352];
  int tid=threadIdx.x, bid=blockIdx.x;
  int wave=__builtin_amdgcn_readfirstlane((int)(tid>>6));
  int l=tid&63;
  int r0=bid*32+wave*8;
  bool act = (l < 27);
  float acc[8];
  #pragma unroll
  for (int i=0;i<8;i++) acc[i] = act ? tagb[l] : 0.f;
  const float* hfr[8]; const float* hbr[8]; const float* cr[8]; const float* fr[8];
  #pragma unroll
  for (int i=0;i<8;i++){
    int r=r0+i; int b=r>>7, sw=r&127;
    hfr[i]=hsf + (size_t)(sw*128+b)*256;
    hbr[i]=hsb + (size_t)(sw*128+b)*256;
    cr[i]=chvec + (size_t)r*64;
    fr[i]=fvb + (size_t)r*128;
  }
  for (int i=tid;i<27*88;i+=256){
    int rr=i/88, k4=i%88;
    *(float4*)&Wt[(rr*352+k4*4)^((rr&7)<<2)] = *(const float4*)(tagW + rr*704 + k4*4);
  }
  __syncthreads();
  if (act){
    for (int k4=0;k4<64;k4++){
      float4 w=*(const float4*)&Wt[(l*352+k4*4)^((l&7)<<2)];
      #pragma unroll
      for (int i=0;i<8;i++){
        const float4 x=*(const float4*)(hfr[i]+k4*4);
        acc[i]=fmaf(x.x,w.x,fmaf(x.y,w.y,fmaf(x.z,w.z,fmaf(x.w,w.w,acc[i]))));
      }
    }
    for (int k4=64;k4<88;k4++){
      float4 w=*(const float4*)&Wt[(l*352+k4*4)^((l&7)<<2)];
      #pragma unroll
      for (int i=0;i<8;i++){
        const float4 x=*(const float4*)(hbr[i]+(k4-64)*4);
        acc[i]=fmaf(x.x,w.x,fmaf(x.y,w.y,fmaf(x.z,w.z,fmaf(x.w,w.w,acc[i]))));
      }
    }
  }
  __syncthreads();
  for (int i=tid;i<27*88;i+=256){
    int rr=i/88, k4=i%88;
    *(float4*)&Wt[(rr*352+k4*4)^((rr&7)<<2)] = *(const float4*)(tagW + rr*704 + 352 + k4*4);
  }
  __syncthreads();
  if (act){
    for (int k4=0;k4<40;k4++){
      float4 w=*(const float4*)&Wt[(l*352+k4*4)^((l&7)<<2)];
      #pragma unroll
      for (int i=0;i<8;i++){
        const float4 x=*(const float4*)(hbr[i]+96+k4*4);
        acc[i]=fmaf(x.x,w.x,fmaf(x.y,w.y,fmaf(x.z,w.z,fmaf(x.w,w.w,acc[i]))));
      }
    }
    for (int k4=40;k4<56;k4++){
      float4 w=*(const float4*)&Wt[(l*352+k4*4)^((l&7)<<2)];
      #pragma unroll
      for (int i=0;i<8;i++){
        const float4 x=*(const float4*)(cr[i]+(k4-40)*4);
        acc[i]=fmaf(x.x,w.x,fmaf(x.y,w.y,fmaf(x.z,w.z,fmaf(x.w,w.w,acc[i]))));
      }
    }
    for (int k4=56;k4<88;k4++){
      float4 w=*(const float4*)&Wt[(l*352+k4*4)^((l&7)<<2)];
      #pragma unroll
      for (int i=0;i<8;i++){
        const float4 x=*(const float4*)(fr[i]+(k4-56)*4);
        acc[i]=fmaf(x.x,w.x,fmaf(x.y,w.y,fmaf(x.z,w.z,fmaf(x.w,w.w,acc[i]))));
      }
    }
    #pragma unroll
    for (int i=0;i<8;i++) feats[(size_t)(r0+i)*27 + l] = acc[i];
  }
}

// ---------------------------------------------------------------------------
__global__ __launch_bounds__(256) void k_argmax(const float* __restrict__ feats,
                                                float* __restrict__ out)
{
  int r = blockIdx.x*256 + threadIdx.x;
  const float* f = feats + (size_t)r*27;
  float best = f[0]; int bi = 0;
  #pragma unroll
  for (int j=1;j<27;j++){ float v=f[j]; if (v>best){best=v;bi=j;} }
  out[r] = (float)bi;
}

// ---------------------------------------------------------------------------
__global__ __launch_bounds__(64) void k_viterbi(
  const float* __restrict__ feats, const int* __restrict__ mask,
  const float* __restrict__ trans, float* __restrict__ out)
{
  __shared__ float tr[729];
  __shared__ unsigned char bp[127][27];
  __shared__ int tags[128];
  int b = blockIdx.x, l = threadIdx.x;
  for (int i=l;i<729;i+=64) tr[i]=trans[i];
  __syncthreads();
  int ll = (l<27) ? l : 0;
  float trc[27];
  #pragma unroll
  for (int i=0;i<27;i++) trc[i]=tr[i*27+ll];
  const float* fb_ = feats + (size_t)b*128*27;
  float score = fb_[ll] + tr[25*27 + ll];
  for (int t=1;t<128;t++){
    float best=-3.0e38f; int bi=0;
    #pragma unroll 1
    for (int i=0;i<27;i++){
      float si = __shfl(score, i, 64);
      float cand = si + trc[i];
      if (cand > best){ best=cand; bi=i; }
    }
    int m = mask[b*128 + t];
    float ns = best + fb_[t*27 + ll];
    if (m) score = ns;
    int bpv = m ? bi : ll;
    if (l < 27) bp[t-1][l] = (unsigned char)bpv;
  }
  float fin = score + tr[ll*27 + 26];
  if (l >= 27) fin = -3.0e38f;
  float bestf=-3.0e38f; int bt=0;
  #pragma unroll 1
  for (int i=0;i<27;i++){
    float v=__shfl(fin, i, 64);
    if (v > bestf){ bestf=v; bt=i; }
  }
  if (l==0){
    out[b]=bestf;
    int tg=bt; tags[127]=tg;
    for (int t=126;t>=0;t--){ tg = bp[t][tg]; tags[t]=tg; }
  }
  __syncthreads();
  float* op = out + 128 + b*128;
  for (int t=l;t<128;t+=64) op[t]=(float)tags[t];
}

// ---------------------------------------------------------------------------
extern "C" void kernel_launch(void* const* d_in, const int* in_sizes, int n_in,
                              void* d_out, int out_size, void* d_ws, size_t ws_size,
                              hipStream_t stream)
{
  (void)in_sizes; (void)n_in; (void)out_size; (void)ws_size;
  const int*   words2ix = (const int*)d_in[0];
  const int*   chars2ix = (const int*)d_in[1];
  const float* features = (const float*)d_in[2];
  const int*   amask    = (const int*)d_in[3];
  const float* word_emb = (const float*)d_in[4];
  const float* char_emb = (const float*)d_in[5];
  const float* cWih_f=(const float*)d_in[6],  *cWhh_f=(const float*)d_in[7];
  const float* cbih_f=(const float*)d_in[8],  *cbhh_f=(const float*)d_in[9];
  const float* cWih_b=(const float*)d_in[10], *cWhh_b=(const float*)d_in[11];
  const float* cbih_b=(const float*)d_in[12], *cbhh_b=(const float*)d_in[13];
  const float* coW=(const float*)d_in[14], *cob=(const float*)d_in[15];
  const float* fW =(const float*)d_in[16], *fb =(const float*)d_in[17];
  const float* lWih_f=(const float*)d_in[18], *lWhh_f=(const float*)d_in[19];
  const float* lbih_f=(const float*)d_in[20], *lbhh_f=(const float*)d_in[21];
  const float* lWih_b=(const float*)d_in[22], *lWhh_b=(const float*)d_in[23];
  const float* lbih_b=(const float*)d_in[24], *lbhh_b=(const float*)d_in[25];
  const float* tagW=(const float*)d_in[26], *tagb=(const float*)d_in[27];
  const float* trans=(const float*)d_in[28];
  float* out = (float*)d_out;

  float* p = (float*)d_ws;
  float* chvec = p; p += 16384*64;
  float* fvb   = p; p += 16384*128;
  float* gxf   = p; p += (size_t)16384*1024;
  float* gxb   = p; p += (size_t)16384*1024;
  float* chh   = p; p += 2*16384*64;
  float* tab   = p; p += 2*500*256;
  float* hA    = p; p += 2*128*256;
  float* hB    = p; p += 2*128*256;
  float* hsf   = p; p += (size_t)128*128*256;
  float* hsb   = p; p += (size_t)128*128*256;
  float* feats = p; p += 16384*27;
  unsigned int* cnt = (unsigned int*)p;

  hipMemsetAsync(cnt, 0, 64*sizeof(unsigned int), stream);

  k_gxc<<<1000,256,0,stream>>>(char_emb, cWih_f,cbih_f,cbhh_f, cWih_b,cbih_b,cbhh_b, tab);
  k_fv<<<8192,256,0,stream>>>(features, fW, fb, fvb);
  k_char<<<1024,256,0,stream>>>(chars2ix, cWhh_f, cWhh_b, tab, chh);
  k_chvec<<<256,256,0,stream>>>(chh, coW, cob, chvec);
  k_gxall<<<2048,256,0,stream>>>(words2ix, word_emb, chvec, fvb,
      lWih_f,lbih_f,lbhh_f, lWih_b,lbih_b,lbhh_b, gxf, gxb);
  k_sent<<<256,256,0,stream>>>(gxf, gxb, lWhh_f, lWhh_b, hA, hB, hsf, hsb, cnt);
  k_feats<<<512,256,0,stream>>>(hsf, hsb, chvec, fvb, tagW, tagb, feats);
  k_argmax<<<64,256,0,stream>>>(feats, out + 128 + 16384);
  k_viterbi<<<128,64,0,stream>>>(feats, amask, trans, out);
}

// Round 4
// 16555.237 us; speedup vs baseline: 1.7642x; 1.7642x over previous
//
#include <hip/hip_runtime.h>
#include <stddef.h>

// BiLSTM-CRF, round 4.
// Round-3 post-mortem: k_sent barrier false-sharing + per-wave threadfence
// (L2 writeback) caused 41 GB HBM traffic; k_char spilled (VGPR=256 cap,
// 6 GB scratch writes). Fixes: padded counters + fence-free release protocol;
// k_char thread-per-gate-row with Whh row in registers.

__device__ __forceinline__ float sigm(float x){ return 1.0f/(1.0f + expf(-x)); }

// ---------------------------------------------------------------------------
// fv[b*S+s][j] = feat_b[j] + sum_f features[b][f][s] * feat_W[j][f]
__global__ __launch_bounds__(256) void k_fv(const float* __restrict__ feat,
                                            const float* __restrict__ fW,
                                            const float* __restrict__ fb,
                                            float* __restrict__ fvb)
{
  int idx = blockIdx.x*256 + threadIdx.x;
  int j = idx & 127;
  int r = idx >> 7;
  int b = r >> 7, sw = r & 127;
  const float* x = feat + b*512 + sw;
  float a = fb[j];
  a = fmaf(x[0],   fW[j*4+0], a);
  a = fmaf(x[128], fW[j*4+1], a);
  a = fmaf(x[256], fW[j*4+2], a);
  a = fmaf(x[384], fW[j*4+3], a);
  fvb[idx] = a;
}

// ---------------------------------------------------------------------------
// tab[d][c][gi] = bih[orig]+bhh[orig] + dot(Wih[orig], char_emb[c])   (gi unit-major)
__global__ __launch_bounds__(256) void k_gxc(
  const float* __restrict__ char_emb,
  const float* __restrict__ Wih_f, const float* __restrict__ bih_f, const float* __restrict__ bhh_f,
  const float* __restrict__ Wih_b, const float* __restrict__ bih_b, const float* __restrict__ bhh_b,
  float* __restrict__ tab)
{
  int idx = blockIdx.x*256 + threadIdx.x;   // 2*500*256
  int gi = idx & 255;
  int c  = (idx >> 8) % 500;
  int d  = idx / (500*256);
  const float* Wih = d ? Wih_b : Wih_f;
  int orig = (gi&3)*64 + (gi>>2);
  const float* w = Wih + orig*64;
  const float* e = char_emb + c*64;
  float a = (d?bih_b:bih_f)[orig] + (d?bhh_b:bhh_f)[orig];
  #pragma unroll 8
  for (int k=0;k<64;k++) a = fmaf(w[k], e[k], a);
  tab[idx] = a;
}

// ---------------------------------------------------------------------------
// All 16 char-LSTM steps, one kernel, no spills.
// Grid 4096 = dir(2) x 2048 chunks of 8 seqs. Thread tid owns gate row tid
// (unit-major gi: unit=tid>>2, type=tid&3); its Whh row (64 f) in REGISTERS.
// h for the 8 seqs lives in LDS (broadcast reads); gates exchanged via gbuf.
__global__ __launch_bounds__(256) void k_char(
  const int* __restrict__ chars2ix,
  const float* __restrict__ Whh_f, const float* __restrict__ Whh_b,
  const float* __restrict__ tab, float* __restrict__ chh)
{
  __shared__ __align__(16) float hbuf[8][64];   // 2 KB
  __shared__ float gbuf[8][256];                // 8 KB
  int tid = threadIdx.x, bid = blockIdx.x;
  int dir = bid >> 11, chunk = bid & 2047;
  int seq0 = chunk*8;
  const float* Whh = dir ? Whh_b : Whh_f;
  int orig = (tid&3)*64 + (tid>>2);
  float4 wr[16];
  #pragma unroll
  for (int k4=0;k4<16;k4++) wr[k4] = *(const float4*)(Whh + orig*64 + k4*4);
  for (int i=tid;i<8*64;i+=256) ((float*)hbuf)[i]=0.f;
  __syncthreads();
  const float* tb = tab + (size_t)dir*500*256;
  int u = tid & 63;
  int s0 = tid >> 6;          // handles seqs s0 and s0+4 in activation
  float c0 = 0.f, c1 = 0.f;

  for (int t=0;t<16;t++){
    int tpos = dir ? 15-t : t;
    float acc[8];
    #pragma unroll
    for (int i=0;i<8;i++)
      acc[i] = tb[(size_t)chars2ix[(seq0+i)*16 + tpos]*256 + tid];
    #pragma unroll
    for (int k4=0;k4<16;k4++){
      float4 w = wr[k4];
      #pragma unroll
      for (int i=0;i<8;i++){
        const float4 h = *(const float4*)&hbuf[i][k4*4];
        acc[i] = fmaf(h.x,w.x, fmaf(h.y,w.y, fmaf(h.z,w.z, fmaf(h.w,w.w, acc[i]))));
      }
    }
    #pragma unroll
    for (int i=0;i<8;i++) gbuf[i][tid] = acc[i];
    __syncthreads();   // gates visible; all h(t) reads complete
    float gi0=gbuf[s0  ][u*4+0], gf0=gbuf[s0  ][u*4+1], gg0=gbuf[s0  ][u*4+2], go0=gbuf[s0  ][u*4+3];
    float gi1=gbuf[s0+4][u*4+0], gf1=gbuf[s0+4][u*4+1], gg1=gbuf[s0+4][u*4+2], go1=gbuf[s0+4][u*4+3];
    c0 = sigm(gf0)*c0 + sigm(gi0)*tanhf(gg0);
    c1 = sigm(gf1)*c1 + sigm(gi1)*tanhf(gg1);
    hbuf[s0  ][u] = sigm(go0)*tanhf(c0);
    hbuf[s0+4][u] = sigm(go1)*tanhf(c1);
    __syncthreads();   // h(t+1) visible before next step's reads
  }
  #pragma unroll
  for (int i=0;i<2;i++){
    int sq = s0 + i*4;
    chh[(size_t)(dir*16384 + seq0 + sq)*64 + u] = hbuf[sq][u];
  }
}

// ---------------------------------------------------------------------------
// chvec[r][j] = b2[j] + [hf|hb] @ W2[j]
__global__ __launch_bounds__(256) void k_chvec(
  const float* __restrict__ chh,
  const float* __restrict__ W2, const float* __restrict__ b2,
  float* __restrict__ chvec)
{
  __shared__ __align__(16) float Wc[64*128];
  __shared__ __align__(16) float gout[4][8][64];
  int tid = threadIdx.x, bid = blockIdx.x;
  for (int i=tid;i<64*32;i+=256){
    int l2=i>>5, k4=i&31;
    *(float4*)&Wc[(l2*128 + k4*4) ^ ((l2&7)<<2)] = *(const float4*)(W2 + l2*128 + k4*4);
  }
  __syncthreads();
  int wave = __builtin_amdgcn_readfirstlane((int)(tid>>6));
  int l = tid & 63;
  float bb = b2[l];
  for (int it=0; it<2; ++it){
    int r0 = bid*64 + it*32 + wave*8;
    float acc[8];
    #pragma unroll
    for (int i=0;i<8;i++) acc[i]=bb;
    const float* hf[8]; const float* hb[8];
    #pragma unroll
    for (int i=0;i<8;i++){ hf[i]=chh+(size_t)(r0+i)*64; hb[i]=chh+(size_t)(16384+r0+i)*64; }
    #pragma unroll
    for (int k4=0;k4<16;k4++){
      float4 w=*(const float4*)&Wc[(l*128+k4*4)^((l&7)<<2)];
      #pragma unroll
      for (int i=0;i<8;i++){
        const float4 x=*(const float4*)(hf[i]+k4*4);
        acc[i]=fmaf(x.x,w.x,fmaf(x.y,w.y,fmaf(x.z,w.z,fmaf(x.w,w.w,acc[i]))));
      }
    }
    #pragma unroll
    for (int k4=0;k4<16;k4++){
      float4 w=*(const float4*)&Wc[(l*128+64+k4*4)^((l&7)<<2)];
      #pragma unroll
      for (int i=0;i<8;i++){
        const float4 x=*(const float4*)(hb[i]+k4*4);
        acc[i]=fmaf(x.x,w.x,fmaf(x.y,w.y,fmaf(x.z,w.z,fmaf(x.w,w.w,acc[i]))));
      }
    }
    #pragma unroll
    for (int i=0;i<8;i++) gout[wave][i][l]=acc[i];
    int rsub=l>>3, cg=l&7;
    #pragma unroll
    for (int i2=0;i2<2;i2++){
      int col=cg*8+i2*4;
      *(float4*)&chvec[(size_t)(r0+rsub)*64+col] = *(const float4*)&gout[wave][rsub][col];
    }
  }
}

// ---------------------------------------------------------------------------
// Fused input GEMM: gx[dir][s*128+b][gi] = bias + vec(we|chvec|fv) @ Wih^T
__global__ __launch_bounds__(256) void k_gxall(
  const int* __restrict__ words2ix, const float* __restrict__ word_emb,
  const float* __restrict__ chvec, const float* __restrict__ fvb,
  const float* __restrict__ Wih_f, const float* __restrict__ bih_f, const float* __restrict__ bhh_f,
  const float* __restrict__ Wih_b, const float* __restrict__ bih_b, const float* __restrict__ bhh_b,
  float* __restrict__ gxf, float* __restrict__ gxb)
{
  __shared__ __align__(16) float Wg[64*160];   // 40 KB per phase
  __shared__ float bsum[64];
  __shared__ __align__(16) float gout[4][8][64];
  int tid=threadIdx.x, bid=blockIdx.x;
  int ct = bid & 15, dir = (bid>>4)&1, rch = bid>>5;
  const float* Wih = dir ? Wih_b : Wih_f;
  float* gx = dir ? gxb : gxf;
  if (tid<64){
    int gi = ct*64 + tid, orig = (gi&3)*256 + (gi>>2);
    bsum[tid] = (dir?bih_b:bih_f)[orig] + (dir?bhh_b:bhh_f)[orig];
  }
  __syncthreads();
  int wave = __builtin_amdgcn_readfirstlane((int)(tid>>6));
  int l = tid & 63;
  for (int it=0; it<8; ++it){
    int r0 = rch*256 + it*32 + wave*8;
    float acc[8];
    const float *wp[8], *cp[8], *fp[8];
    #pragma unroll
    for (int i=0;i<8;i++){
      int r=r0+i; int b=r&127, sw=r>>7; int rid=b*128+sw;
      wp[i] = word_emb + (size_t)words2ix[rid]*128;
      cp[i] = chvec + (size_t)rid*64;
      fp[i] = fvb + (size_t)rid*128;
    }
    {
      float bb = bsum[l];
      #pragma unroll
      for (int i=0;i<8;i++) acc[i]=bb;
    }
    __syncthreads();
    for (int i=tid; i<64*40; i+=256){
      int g = i/40, k4 = i%40;
      int gi = ct*64+g, orig = (gi&3)*256 + (gi>>2);
      *(float4*)&Wg[(g*160 + k4*4) ^ ((g&7)<<2)] = *(const float4*)(Wih + orig*320 + k4*4);
    }
    __syncthreads();
    #pragma unroll
    for (int k4=0;k4<32;k4++){
      float4 w=*(const float4*)&Wg[(l*160 + k4*4) ^ ((l&7)<<2)];
      #pragma unroll
      for (int i=0;i<8;i++){
        const float4 x=*(const float4*)(wp[i]+k4*4);
        acc[i]=fmaf(x.x,w.x,fmaf(x.y,w.y,fmaf(x.z,w.z,fmaf(x.w,w.w,acc[i]))));
      }
    }
    #pragma unroll
    for (int k4=32;k4<40;k4++){
      float4 w=*(const float4*)&Wg[(l*160 + k4*4) ^ ((l&7)<<2)];
      #pragma unroll
      for (int i=0;i<8;i++){
        const float4 x=*(const float4*)(cp[i]+(k4-32)*4);
        acc[i]=fmaf(x.x,w.x,fmaf(x.y,w.y,fmaf(x.z,w.z,fmaf(x.w,w.w,acc[i]))));
      }
    }
    __syncthreads();
    for (int i=tid; i<64*40; i+=256){
      int g = i/40, k4 = i%40;
      int gi = ct*64+g, orig = (gi&3)*256 + (gi>>2);
      *(float4*)&Wg[(g*160 + k4*4) ^ ((g&7)<<2)] = *(const float4*)(Wih + orig*320 + 160 + k4*4);
    }
    __syncthreads();
    #pragma unroll
    for (int k4=0;k4<8;k4++){
      float4 w=*(const float4*)&Wg[(l*160 + k4*4) ^ ((l&7)<<2)];
      #pragma unroll
      for (int i=0;i<8;i++){
        const float4 x=*(const float4*)(cp[i]+32+k4*4);
        acc[i]=fmaf(x.x,w.x,fmaf(x.y,w.y,fmaf(x.z,w.z,fmaf(x.w,w.w,acc[i]))));
      }
    }
    #pragma unroll
    for (int k4=8;k4<40;k4++){
      float4 w=*(const float4*)&Wg[(l*160 + k4*4) ^ ((l&7)<<2)];
      #pragma unroll
      for (int i=0;i<8;i++){
        const float4 x=*(const float4*)(fp[i]+(k4-8)*4);
        acc[i]=fmaf(x.x,w.x,fmaf(x.y,w.y,fmaf(x.z,w.z,fmaf(x.w,w.w,acc[i]))));
      }
    }
    #pragma unroll
    for (int i=0;i<8;i++) gout[wave][i][l]=acc[i];
    int rsub=l>>3, cg=l&7;
    #pragma unroll
    for (int i2=0;i2<2;i2++){
      int col=cg*8+i2*4;
      *(float4*)&gx[(size_t)(r0+rsub)*1024 + ct*64 + col] = *(const float4*)&gout[wave][rsub][col];
    }
  }
}

// ---------------------------------------------------------------------------
// Persistent sentence BiLSTM. grid 256 (1 WG/CU via 140 KB LDS).
// Group = 8 WGs sharing (dir,chunk). Barrier protocol (fence-free):
//  - h stores are agent-scope relaxed atomics (reach coherence point);
//  - __syncthreads drains vmcnt(0) -> stores acked before tid0's counter add;
//  - counters padded to 256 B/group; relaxed polls + s_sleep backoff.
__global__ __launch_bounds__(256) void k_sent(
  const float* __restrict__ gxf, const float* __restrict__ gxb,
  const float* __restrict__ Whh_f, const float* __restrict__ Whh_b,
  float* __restrict__ hA, float* __restrict__ hB,
  float* __restrict__ hsf, float* __restrict__ hsb,
  unsigned int* __restrict__ cnt)
{
  __shared__ __align__(16) float Wl[128*256];   // 128 KB
  __shared__ __align__(16) float hstage[8][256];// 8 KB
  __shared__ float gbuf[4][64][4];              // 4 KB
  int tid=threadIdx.x, bid=blockIdx.x;
  int gt = bid & 7, dir = (bid>>3)&1, chunk = bid>>4;
  int grp = bid >> 3;    // 0..31
  unsigned int* ctr = cnt + (grp<<6);   // 256 B apart
  const float* Whh = dir ? Whh_b : Whh_f;
  const float* gx  = dir ? gxb : gxf;
  float* hs = dir ? hsb : hsf;
  int b0 = chunk*8;
  for (int i=tid; i<128*64; i+=256){
    int g = i>>6, k4 = i&63;
    int gi = gt*128 + g, orig = (gi&3)*256 + (gi>>2);
    *(float4*)&Wl[(g*256 + k4*4) ^ ((g&7)<<2)] = *(const float4*)(Whh + orig*256 + k4*4);
  }
  for (int i=tid; i<2048; i+=256) ((float*)hstage)[i] = 0.f;
  __syncthreads();
  int wave = __builtin_amdgcn_readfirstlane((int)(tid>>6));
  int l = tid & 63;
  int gsl = wave >> 1, rg = wave & 1;
  int grow = gsl*64 + l;
  int ul = l & 15, rsel = l >> 4;
  int au = gt*32 + gsl*16 + ul;
  int ar = rg*4 + rsel;
  float creg = 0.f;
  float nxt[4];
  {
    int spos0 = dir ? 127 : 0;
    #pragma unroll
    for (int i=0;i<4;i++)
      nxt[i] = gx[(size_t)(spos0*128 + b0 + rg*4 + i)*1024 + gt*128 + grow];
  }
  for (int t=0; t<128; ++t){
    int spos = dir ? 127 - t : t;
    float acc[4];
    #pragma unroll
    for (int i=0;i<4;i++) acc[i] = nxt[i];
    #pragma unroll
    for (int k4=0;k4<64;k4++){
      float4 w = *(const float4*)&Wl[(grow*256 + k4*4) ^ ((grow&7)<<2)];
      #pragma unroll
      for (int i=0;i<4;i++){
        const float4 x = *(const float4*)&hstage[rg*4 + i][k4*4];
        acc[i] = fmaf(x.x,w.x, fmaf(x.y,w.y, fmaf(x.z,w.z, fmaf(x.w,w.w, acc[i]))));
      }
    }
    if (t < 127){
      int sposn = dir ? 126 - t : t+1;
      #pragma unroll
      for (int i=0;i<4;i++)
        nxt[i] = gx[(size_t)(sposn*128 + b0 + rg*4 + i)*1024 + gt*128 + grow];
    }
    #pragma unroll
    for (int i=0;i<4;i++) gbuf[wave][l][i] = acc[i];
    // same-wave exchange
    float g_i = gbuf[wave][ul*4+0][rsel];
    float g_f = gbuf[wave][ul*4+1][rsel];
    float g_g = gbuf[wave][ul*4+2][rsel];
    float g_o = gbuf[wave][ul*4+3][rsel];
    creg = sigm(g_f)*creg + sigm(g_i)*tanhf(g_g);
    float h = sigm(g_o)*tanhf(creg);
    float* hn = ((t&1)==0) ? hB : hA;
    __hip_atomic_store(&hn[(size_t)(dir*128 + b0 + ar)*256 + au], h,
                       __ATOMIC_RELAXED, __HIP_MEMORY_SCOPE_AGENT);
    hs[(size_t)(spos*128 + b0 + ar)*256 + au] = h;
    __syncthreads();   // drains vmcnt(0): all h stores acked at coherence point
    if (tid==0){
      atomicAdd(ctr, 1u);
      unsigned int target = 8u*(unsigned)(t+1);
      while (__hip_atomic_load(ctr, __ATOMIC_RELAXED, __HIP_MEMORY_SCOPE_AGENT) < target)
        __builtin_amdgcn_s_sleep(1);
    }
    __syncthreads();
    if (t < 127){
      const float* hc = ((t&1)==0) ? hB : hA;
      #pragma unroll
      for (int i=0;i<8;i++){
        unsigned int v = __hip_atomic_load(
          (const unsigned int*)&hc[(size_t)(dir*128 + b0 + i)*256 + tid],
          __ATOMIC_RELAXED, __HIP_MEMORY_SCOPE_AGENT);
        hstage[i][tid] = __uint_as_float(v);
      }
      __syncthreads();
    }
  }
}

// ---------------------------------------------------------------------------
// feats[b*128+s][k] = tag_b[k] + [hsf|hsb|chvec|fv] . tag_W[k]  (K=704, 2 passes)
__global__ __launch_bounds__(256) void k_feats(
  const float* __restrict__ hsf, const float* __restrict__ hsb,
  const float* __restrict__ chvec, const float* __restrict__ fvb,
  const float* __restrict__ tagW, const float* __restrict__ tagb,
  float* __restrict__ feats)
{
  __shared__ __align__(16) float Wt[27*352];
  int tid=threadIdx.x, bid=blockIdx.x;
  int wave=__builtin_amdgcn_readfirstlane((int)(tid>>6));
  int l=tid&63;
  int r0=bid*32+wave*8;
  bool act = (l < 27);
  float acc[8];
  #pragma unroll
  for (int i=0;i<8;i++) acc[i] = act ? tagb[l] : 0.f;
  const float* hfr[8]; const float* hbr[8]; const float* cr[8]; const float* fr[8];
  #pragma unroll
  for (int i=0;i<8;i++){
    int r=r0+i; int b=r>>7, sw=r&127;
    hfr[i]=hsf + (size_t)(sw*128+b)*256;
    hbr[i]=hsb + (size_t)(sw*128+b)*256;
    cr[i]=chvec + (size_t)r*64;
    fr[i]=fvb + (size_t)r*128;
  }
  for (int i=tid;i<27*88;i+=256){
    int rr=i/88, k4=i%88;
    *(float4*)&Wt[(rr*352+k4*4)^((rr&7)<<2)] = *(const float4*)(tagW + rr*704 + k4*4);
  }
  __syncthreads();
  if (act){
    for (int k4=0;k4<64;k4++){
      float4 w=*(const float4*)&Wt[(l*352+k4*4)^((l&7)<<2)];
      #pragma unroll
      for (int i=0;i<8;i++){
        const float4 x=*(const float4*)(hfr[i]+k4*4);
        acc[i]=fmaf(x.x,w.x,fmaf(x.y,w.y,fmaf(x.z,w.z,fmaf(x.w,w.w,acc[i]))));
      }
    }
    for (int k4=64;k4<88;k4++){
      float4 w=*(const float4*)&Wt[(l*352+k4*4)^((l&7)<<2)];
      #pragma unroll
      for (int i=0;i<8;i++){
        const float4 x=*(const float4*)(hbr[i]+(k4-64)*4);
        acc[i]=fmaf(x.x,w.x,fmaf(x.y,w.y,fmaf(x.z,w.z,fmaf(x.w,w.w,acc[i]))));
      }
    }
  }
  __syncthreads();
  for (int i=tid;i<27*88;i+=256){
    int rr=i/88, k4=i%88;
    *(float4*)&Wt[(rr*352+k4*4)^((rr&7)<<2)] = *(const float4*)(tagW + rr*704 + 352 + k4*4);
  }
  __syncthreads();
  if (act){
    for (int k4=0;k4<40;k4++){
      float4 w=*(const float4*)&Wt[(l*352+k4*4)^((l&7)<<2)];
      #pragma unroll
      for (int i=0;i<8;i++){
        const float4 x=*(const float4*)(hbr[i]+96+k4*4);
        acc[i]=fmaf(x.x,w.x,fmaf(x.y,w.y,fmaf(x.z,w.z,fmaf(x.w,w.w,acc[i]))));
      }
    }
    for (int k4=40;k4<56;k4++){
      float4 w=*(const float4*)&Wt[(l*352+k4*4)^((l&7)<<2)];
      #pragma unroll
      for (int i=0;i<8;i++){
        const float4 x=*(const float4*)(cr[i]+(k4-40)*4);
        acc[i]=fmaf(x.x,w.x,fmaf(x.y,w.y,fmaf(x.z,w.z,fmaf(x.w,w.w,acc[i]))));
      }
    }
    for (int k4=56;k4<88;k4++){
      float4 w=*(const float4*)&Wt[(l*352+k4*4)^((l&7)<<2)];
      #pragma unroll
      for (int i=0;i<8;i++){
        const float4 x=*(const float4*)(fr[i]+(k4-56)*4);
        acc[i]=fmaf(x.x,w.x,fmaf(x.y,w.y,fmaf(x.z,w.z,fmaf(x.w,w.w,acc[i]))));
      }
    }
    #pragma unroll
    for (int i=0;i<8;i++) feats[(size_t)(r0+i)*27 + l] = acc[i];
  }
}

// ---------------------------------------------------------------------------
__global__ __launch_bounds__(256) void k_argmax(const float* __restrict__ feats,
                                                float* __restrict__ out)
{
  int r = blockIdx.x*256 + threadIdx.x;
  const float* f = feats + (size_t)r*27;
  float best = f[0]; int bi = 0;
  #pragma unroll
  for (int j=1;j<27;j++){ float v=f[j]; if (v>best){best=v;bi=j;} }
  out[r] = (float)bi;
}

// ---------------------------------------------------------------------------
__global__ __launch_bounds__(64) void k_viterbi(
  const float* __restrict__ feats, const int* __restrict__ mask,
  const float* __restrict__ trans, float* __restrict__ out)
{
  __shared__ float tr[729];
  __shared__ unsigned char bp[127][27];
  __shared__ int tags[128];
  int b = blockIdx.x, l = threadIdx.x;
  for (int i=l;i<729;i+=64) tr[i]=trans[i];
  __syncthreads();
  int ll = (l<27) ? l : 0;
  float trc[27];
  #pragma unroll
  for (int i=0;i<27;i++) trc[i]=tr[i*27+ll];
  const float* fb_ = feats + (size_t)b*128*27;
  float score = fb_[ll] + tr[25*27 + ll];
  for (int t=1;t<128;t++){
    float best=-3.0e38f; int bi=0;
    #pragma unroll 1
    for (int i=0;i<27;i++){
      float si = __shfl(score, i, 64);
      float cand = si + trc[i];
      if (cand > best){ best=cand; bi=i; }
    }
    int m = mask[b*128 + t];
    float ns = best + fb_[t*27 + ll];
    if (m) score = ns;
    int bpv = m ? bi : ll;
    if (l < 27) bp[t-1][l] = (unsigned char)bpv;
  }
  float fin = score + tr[ll*27 + 26];
  if (l >= 27) fin = -3.0e38f;
  float bestf=-3.0e38f; int bt=0;
  #pragma unroll 1
  for (int i=0;i<27;i++){
    float v=__shfl(fin, i, 64);
    if (v > bestf){ bestf=v; bt=i; }
  }
  if (l==0){
    out[b]=bestf;
    int tg=bt; tags[127]=tg;
    for (int t=126;t>=0;t--){ tg = bp[t][tg]; tags[t]=tg; }
  }
  __syncthreads();
  float* op = out + 128 + b*128;
  for (int t=l;t<128;t+=64) op[t]=(float)tags[t];
}

// ---------------------------------------------------------------------------
extern "C" void kernel_launch(void* const* d_in, const int* in_sizes, int n_in,
                              void* d_out, int out_size, void* d_ws, size_t ws_size,
                              hipStream_t stream)
{
  (void)in_sizes; (void)n_in; (void)out_size; (void)ws_size;
  const int*   words2ix = (const int*)d_in[0];
  const int*   chars2ix = (const int*)d_in[1];
  const float* features = (const float*)d_in[2];
  const int*   amask    = (const int*)d_in[3];
  const float* word_emb = (const float*)d_in[4];
  const float* char_emb = (const float*)d_in[5];
  const float* cWih_f=(const float*)d_in[6],  *cWhh_f=(const float*)d_in[7];
  const float* cbih_f=(const float*)d_in[8],  *cbhh_f=(const float*)d_in[9];
  const float* cWih_b=(const float*)d_in[10], *cWhh_b=(const float*)d_in[11];
  const float* cbih_b=(const float*)d_in[12], *cbhh_b=(const float*)d_in[13];
  const float* coW=(const float*)d_in[14], *cob=(const float*)d_in[15];
  const float* fW =(const float*)d_in[16], *fb =(const float*)d_in[17];
  const float* lWih_f=(const float*)d_in[18], *lWhh_f=(const float*)d_in[19];
  const float* lbih_f=(const float*)d_in[20], *lbhh_f=(const float*)d_in[21];
  const float* lWih_b=(const float*)d_in[22], *lWhh_b=(const float*)d_in[23];
  const float* lbih_b=(const float*)d_in[24], *lbhh_b=(const float*)d_in[25];
  const float* tagW=(const float*)d_in[26], *tagb=(const float*)d_in[27];
  const float* trans=(const float*)d_in[28];
  float* out = (float*)d_out;

  float* p = (float*)d_ws;
  float* chvec = p; p += 16384*64;
  float* fvb   = p; p += 16384*128;
  float* gxf   = p; p += (size_t)16384*1024;
  float* gxb   = p; p += (size_t)16384*1024;
  float* chh   = p; p += 2*16384*64;
  float* tab   = p; p += 2*500*256;
  float* hA    = p; p += 2*128*256;
  float* hB    = p; p += 2*128*256;
  float* hsf   = p; p += (size_t)128*128*256;
  float* hsb   = p; p += (size_t)128*128*256;
  float* feats = p; p += 16384*27;
  unsigned int* cnt = (unsigned int*)p;   // 32 groups x 64 uints (padded)

  hipMemsetAsync(cnt, 0, 32*64*sizeof(unsigned int), stream);

  k_gxc<<<1000,256,0,stream>>>(char_emb, cWih_f,cbih_f,cbhh_f, cWih_b,cbih_b,cbhh_b, tab);
  k_fv<<<8192,256,0,stream>>>(features, fW, fb, fvb);
  k_char<<<4096,256,0,stream>>>(chars2ix, cWhh_f, cWhh_b, tab, chh);
  k_chvec<<<256,256,0,stream>>>(chh, coW, cob, chvec);
  k_gxall<<<2048,256,0,stream>>>(words2ix, word_emb, chvec, fvb,
      lWih_f,lbih_f,lbhh_f, lWih_b,lbih_b,lbhh_b, gxf, gxb);
  k_sent<<<256,256,0,stream>>>(gxf, gxb, lWhh_f, lWhh_b, hA, hB, hsf, hsb, cnt);
  k_feats<<<512,256,0,stream>>>(hsf, hsb, chvec, fvb, tagW, tagb, feats);
  k_argmax<<<64,256,0,stream>>>(feats, out + 128 + 16384);
  k_viterbi<<<128,64,0,stream>>>(feats, amask, trans, out);
}

// Round 5
// 2214.825 us; speedup vs baseline: 13.1866x; 7.4747x over previous
//
#include <hip/hip_runtime.h>
#include <stddef.h>

// BiLSTM-CRF, round 5.
// Round-4 post-mortem: k_sent traffic (41 GB) was kernel-body generated
// (identical across r3/r4): VGPR=256 spill signature + 2048x4B atomic refill.
// This round: k_sent rewritten — 512 thr, acc[2], conflict-free LDS strides,
// coherent dwordx4 (sc0 sc1) refill. Barrier protocol unchanged (proven).

typedef float f32x4 __attribute__((ext_vector_type(4)));

__device__ __forceinline__ float sigm(float x){ return 1.0f/(1.0f + expf(-x)); }

// ---------------------------------------------------------------------------
// fv[b*S+s][j] = feat_b[j] + sum_f features[b][f][s] * feat_W[j][f]
__global__ __launch_bounds__(256) void k_fv(const float* __restrict__ feat,
                                            const float* __restrict__ fW,
                                            const float* __restrict__ fb,
                                            float* __restrict__ fvb)
{
  int idx = blockIdx.x*256 + threadIdx.x;
  int j = idx & 127;
  int r = idx >> 7;
  int b = r >> 7, sw = r & 127;
  const float* x = feat + b*512 + sw;
  float a = fb[j];
  a = fmaf(x[0],   fW[j*4+0], a);
  a = fmaf(x[128], fW[j*4+1], a);
  a = fmaf(x[256], fW[j*4+2], a);
  a = fmaf(x[384], fW[j*4+3], a);
  fvb[idx] = a;
}

// ---------------------------------------------------------------------------
// tab[d][c][gi] = bih[orig]+bhh[orig] + dot(Wih[orig], char_emb[c])   (gi unit-major)
__global__ __launch_bounds__(256) void k_gxc(
  const float* __restrict__ char_emb,
  const float* __restrict__ Wih_f, const float* __restrict__ bih_f, const float* __restrict__ bhh_f,
  const float* __restrict__ Wih_b, const float* __restrict__ bih_b, const float* __restrict__ bhh_b,
  float* __restrict__ tab)
{
  int idx = blockIdx.x*256 + threadIdx.x;   // 2*500*256
  int gi = idx & 255;
  int c  = (idx >> 8) % 500;
  int d  = idx / (500*256);
  const float* Wih = d ? Wih_b : Wih_f;
  int orig = (gi&3)*64 + (gi>>2);
  const float* w = Wih + orig*64;
  const float* e = char_emb + c*64;
  float a = (d?bih_b:bih_f)[orig] + (d?bhh_b:bhh_f)[orig];
  #pragma unroll 8
  for (int k=0;k<64;k++) a = fmaf(w[k], e[k], a);
  tab[idx] = a;
}

// ---------------------------------------------------------------------------
// All 16 char-LSTM steps, one kernel (round-4 version — worked, no spills).
__global__ __launch_bounds__(256) void k_char(
  const int* __restrict__ chars2ix,
  const float* __restrict__ Whh_f, const float* __restrict__ Whh_b,
  const float* __restrict__ tab, float* __restrict__ chh)
{
  __shared__ __align__(16) float hbuf[8][64];   // 2 KB
  __shared__ float gbuf[8][256];                // 8 KB
  int tid = threadIdx.x, bid = blockIdx.x;
  int dir = bid >> 11, chunk = bid & 2047;
  int seq0 = chunk*8;
  const float* Whh = dir ? Whh_b : Whh_f;
  int orig = (tid&3)*64 + (tid>>2);
  float4 wr[16];
  #pragma unroll
  for (int k4=0;k4<16;k4++) wr[k4] = *(const float4*)(Whh + orig*64 + k4*4);
  for (int i=tid;i<8*64;i+=256) ((float*)hbuf)[i]=0.f;
  __syncthreads();
  const float* tb = tab + (size_t)dir*500*256;
  int u = tid & 63;
  int s0 = tid >> 6;          // handles seqs s0 and s0+4 in activation
  float c0 = 0.f, c1 = 0.f;

  for (int t=0;t<16;t++){
    int tpos = dir ? 15-t : t;
    float acc[8];
    #pragma unroll
    for (int i=0;i<8;i++)
      acc[i] = tb[(size_t)chars2ix[(seq0+i)*16 + tpos]*256 + tid];
    #pragma unroll
    for (int k4=0;k4<16;k4++){
      float4 w = wr[k4];
      #pragma unroll
      for (int i=0;i<8;i++){
        const float4 h = *(const float4*)&hbuf[i][k4*4];
        acc[i] = fmaf(h.x,w.x, fmaf(h.y,w.y, fmaf(h.z,w.z, fmaf(h.w,w.w, acc[i]))));
      }
    }
    #pragma unroll
    for (int i=0;i<8;i++) gbuf[i][tid] = acc[i];
    __syncthreads();
    float gi0=gbuf[s0  ][u*4+0], gf0=gbuf[s0  ][u*4+1], gg0=gbuf[s0  ][u*4+2], go0=gbuf[s0  ][u*4+3];
    float gi1=gbuf[s0+4][u*4+0], gf1=gbuf[s0+4][u*4+1], gg1=gbuf[s0+4][u*4+2], go1=gbuf[s0+4][u*4+3];
    c0 = sigm(gf0)*c0 + sigm(gi0)*tanhf(gg0);
    c1 = sigm(gf1)*c1 + sigm(gi1)*tanhf(gg1);
    hbuf[s0  ][u] = sigm(go0)*tanhf(c0);
    hbuf[s0+4][u] = sigm(go1)*tanhf(c1);
    __syncthreads();
  }
  #pragma unroll
  for (int i=0;i<2;i++){
    int sq = s0 + i*4;
    chh[(size_t)(dir*16384 + seq0 + sq)*64 + u] = hbuf[sq][u];
  }
}

// ---------------------------------------------------------------------------
// chvec[r][j] = b2[j] + [hf|hb] @ W2[j]
__global__ __launch_bounds__(256) void k_chvec(
  const float* __restrict__ chh,
  const float* __restrict__ W2, const float* __restrict__ b2,
  float* __restrict__ chvec)
{
  __shared__ __align__(16) float Wc[64*128];
  __shared__ __align__(16) float gout[4][8][64];
  int tid = threadIdx.x, bid = blockIdx.x;
  for (int i=tid;i<64*32;i+=256){
    int l2=i>>5, k4=i&31;
    *(float4*)&Wc[(l2*128 + k4*4) ^ ((l2&7)<<2)] = *(const float4*)(W2 + l2*128 + k4*4);
  }
  __syncthreads();
  int wave = __builtin_amdgcn_readfirstlane((int)(tid>>6));
  int l = tid & 63;
  float bb = b2[l];
  for (int it=0; it<2; ++it){
    int r0 = bid*64 + it*32 + wave*8;
    float acc[8];
    #pragma unroll
    for (int i=0;i<8;i++) acc[i]=bb;
    const float* hf[8]; const float* hb[8];
    #pragma unroll
    for (int i=0;i<8;i++){ hf[i]=chh+(size_t)(r0+i)*64; hb[i]=chh+(size_t)(16384+r0+i)*64; }
    #pragma unroll
    for (int k4=0;k4<16;k4++){
      float4 w=*(const float4*)&Wc[(l*128+k4*4)^((l&7)<<2)];
      #pragma unroll
      for (int i=0;i<8;i++){
        const float4 x=*(const float4*)(hf[i]+k4*4);
        acc[i]=fmaf(x.x,w.x,fmaf(x.y,w.y,fmaf(x.z,w.z,fmaf(x.w,w.w,acc[i]))));
      }
    }
    #pragma unroll
    for (int k4=0;k4<16;k4++){
      float4 w=*(const float4*)&Wc[(l*128+64+k4*4)^((l&7)<<2)];
      #pragma unroll
      for (int i=0;i<8;i++){
        const float4 x=*(const float4*)(hb[i]+k4*4);
        acc[i]=fmaf(x.x,w.x,fmaf(x.y,w.y,fmaf(x.z,w.z,fmaf(x.w,w.w,acc[i]))));
      }
    }
    #pragma unroll
    for (int i=0;i<8;i++) gout[wave][i][l]=acc[i];
    int rsub=l>>3, cg=l&7;
    #pragma unroll
    for (int i2=0;i2<2;i2++){
      int col=cg*8+i2*4;
      *(float4*)&chvec[(size_t)(r0+rsub)*64+col] = *(const float4*)&gout[wave][rsub][col];
    }
  }
}

// ---------------------------------------------------------------------------
// Fused input GEMM: gx[dir][s*128+b][gi] = bias + vec(we|chvec|fv) @ Wih^T
__global__ __launch_bounds__(256) void k_gxall(
  const int* __restrict__ words2ix, const float* __restrict__ word_emb,
  const float* __restrict__ chvec, const float* __restrict__ fvb,
  const float* __restrict__ Wih_f, const float* __restrict__ bih_f, const float* __restrict__ bhh_f,
  const float* __restrict__ Wih_b, const float* __restrict__ bih_b, const float* __restrict__ bhh_b,
  float* __restrict__ gxf, float* __restrict__ gxb)
{
  __shared__ __align__(16) float Wg[64*160];   // 40 KB per phase
  __shared__ float bsum[64];
  __shared__ __align__(16) float gout[4][8][64];
  int tid=threadIdx.x, bid=blockIdx.x;
  int ct = bid & 15, dir = (bid>>4)&1, rch = bid>>5;
  const float* Wih = dir ? Wih_b : Wih_f;
  float* gx = dir ? gxb : gxf;
  if (tid<64){
    int gi = ct*64 + tid, orig = (gi&3)*256 + (gi>>2);
    bsum[tid] = (dir?bih_b:bih_f)[orig] + (dir?bhh_b:bhh_f)[orig];
  }
  __syncthreads();
  int wave = __builtin_amdgcn_readfirstlane((int)(tid>>6));
  int l = tid & 63;
  for (int it=0; it<8; ++it){
    int r0 = rch*256 + it*32 + wave*8;
    float acc[8];
    const float *wp[8], *cp[8], *fp[8];
    #pragma unroll
    for (int i=0;i<8;i++){
      int r=r0+i; int b=r&127, sw=r>>7; int rid=b*128+sw;
      wp[i] = word_emb + (size_t)words2ix[rid]*128;
      cp[i] = chvec + (size_t)rid*64;
      fp[i] = fvb + (size_t)rid*128;
    }
    {
      float bb = bsum[l];
      #pragma unroll
      for (int i=0;i<8;i++) acc[i]=bb;
    }
    __syncthreads();
    for (int i=tid; i<64*40; i+=256){
      int g = i/40, k4 = i%40;
      int gi = ct*64+g, orig = (gi&3)*256 + (gi>>2);
      *(float4*)&Wg[(g*160 + k4*4) ^ ((g&7)<<2)] = *(const float4*)(Wih + orig*320 + k4*4);
    }
    __syncthreads();
    #pragma unroll
    for (int k4=0;k4<32;k4++){
      float4 w=*(const float4*)&Wg[(l*160 + k4*4) ^ ((l&7)<<2)];
      #pragma unroll
      for (int i=0;i<8;i++){
        const float4 x=*(const float4*)(wp[i]+k4*4);
        acc[i]=fmaf(x.x,w.x,fmaf(x.y,w.y,fmaf(x.z,w.z,fmaf(x.w,w.w,acc[i]))));
      }
    }
    #pragma unroll
    for (int k4=32;k4<40;k4++){
      float4 w=*(const float4*)&Wg[(l*160 + k4*4) ^ ((l&7)<<2)];
      #pragma unroll
      for (int i=0;i<8;i++){
        const float4 x=*(const float4*)(cp[i]+(k4-32)*4);
        acc[i]=fmaf(x.x,w.x,fmaf(x.y,w.y,fmaf(x.z,w.z,fmaf(x.w,w.w,acc[i]))));
      }
    }
    __syncthreads();
    for (int i=tid; i<64*40; i+=256){
      int g = i/40, k4 = i%40;
      int gi = ct*64+g, orig = (gi&3)*256 + (gi>>2);
      *(float4*)&Wg[(g*160 + k4*4) ^ ((g&7)<<2)] = *(const float4*)(Wih + orig*320 + 160 + k4*4);
    }
    __syncthreads();
    #pragma unroll
    for (int k4=0;k4<8;k4++){
      float4 w=*(const float4*)&Wg[(l*160 + k4*4) ^ ((l&7)<<2)];
      #pragma unroll
      for (int i=0;i<8;i++){
        const float4 x=*(const float4*)(cp[i]+32+k4*4);
        acc[i]=fmaf(x.x,w.x,fmaf(x.y,w.y,fmaf(x.z,w.z,fmaf(x.w,w.w,acc[i]))));
      }
    }
    #pragma unroll
    for (int k4=8;k4<40;k4++){
      float4 w=*(const float4*)&Wg[(l*160 + k4*4) ^ ((l&7)<<2)];
      #pragma unroll
      for (int i=0;i<8;i++){
        const float4 x=*(const float4*)(fp[i]+(k4-8)*4);
        acc[i]=fmaf(x.x,w.x,fmaf(x.y,w.y,fmaf(x.z,w.z,fmaf(x.w,w.w,acc[i]))));
      }
    }
    #pragma unroll
    for (int i=0;i<8;i++) gout[wave][i][l]=acc[i];
    int rsub=l>>3, cg=l&7;
    #pragma unroll
    for (int i2=0;i2<2;i2++){
      int col=cg*8+i2*4;
      *(float4*)&gx[(size_t)(r0+rsub)*1024 + ct*64 + col] = *(const float4*)&gout[wave][rsub][col];
    }
  }
}

// ---------------------------------------------------------------------------
// Persistent sentence BiLSTM, rewritten. grid 256 x 512 thr (1 WG/CU, 147 KB LDS).
// bid: gt=bid&7 (128-gate tile), dir, chunk (8 batch rows). Group = 8 WGs.
// Wave w owns gate rows w*16..w*16+15; lane l: gl=l&15 (row), ng=l>>4 (row-pair).
// acc[2] per thread. Wl stride 260 / hstage stride 264 -> <=2-way LDS conflicts.
// Cross-WG: 4B agent atomic h-stores; refill via coherent global_load_dwordx4
// (sc0 sc1, bypasses L1/L2); padded counter + s_sleep poll barrier.
__global__ __launch_bounds__(512, 2) void k_sent(
  const float* __restrict__ gxf, const float* __restrict__ gxb,
  const float* __restrict__ Whh_f, const float* __restrict__ Whh_b,
  float* __restrict__ hA, float* __restrict__ hB,
  float* __restrict__ hsf, float* __restrict__ hsb,
  unsigned int* __restrict__ cnt)
{
  __shared__ __align__(16) float Wl[128*260];   // 133,120 B (stride 260: banks 4*gl%32, 2 rows/slot)
  __shared__ __align__(16) float hstage[8*264]; // 8,448 B (stride 264: 2-way max)
  __shared__ float gbuf[8*16*10];               // 5,120 B (stride 10: near conflict-free)
  int tid=threadIdx.x, bid=blockIdx.x;
  int gt = bid & 7, dir = (bid>>3)&1, chunk = bid>>4;
  int grp = bid >> 3;                   // 0..31
  unsigned int* ctr = cnt + (grp<<6);   // 256 B apart
  const float* Whh = dir ? Whh_b : Whh_f;
  const float* gx  = dir ? gxb : gxf;
  float* hs = dir ? hsb : hsf;
  int b0 = chunk*8;

  // stage Whh tile: 128 rows (unit-major) x 64 float4, row stride 260
  for (int i=tid; i<128*64; i+=512){
    int g = i>>6, k4 = i&63;
    int gi = gt*128 + g, orig = (gi&3)*256 + (gi>>2);
    *(float4*)&Wl[g*260 + k4*4] = *(const float4*)(Whh + orig*256 + k4*4);
  }
  for (int i=tid; i<8*264; i+=512) hstage[i] = 0.f;
  __syncthreads();

  int wave = tid>>6, l = tid&63;
  int gl = l & 15, ng = l >> 4;         // ng in 0..3
  int grow = wave*16 + gl;              // gate row 0..127
  // activation mapping (lanes 0..31 active)
  int ul = l >> 3, nn = l & 7;          // ul 0..3, nn 0..7 (valid when l<32)
  int au = gt*32 + wave*4 + ul;         // output unit
  float creg = 0.f;
  float nxt[2];
  {
    int spos0 = dir ? 127 : 0;
    #pragma unroll
    for (int i=0;i<2;i++)
      nxt[i] = gx[(size_t)(spos0*128 + b0 + ng*2 + i)*1024 + gt*128 + grow];
  }

  for (int t=0; t<128; ++t){
    int spos = dir ? 127 - t : t;
    float acc0 = nxt[0], acc1 = nxt[1];
    #pragma unroll 8
    for (int k4=0;k4<64;k4++){
      float4 w  = *(const float4*)&Wl[grow*260 + k4*4];
      float4 x0 = *(const float4*)&hstage[(ng*2+0)*264 + k4*4];
      float4 x1 = *(const float4*)&hstage[(ng*2+1)*264 + k4*4];
      acc0 = fmaf(x0.x,w.x, fmaf(x0.y,w.y, fmaf(x0.z,w.z, fmaf(x0.w,w.w, acc0))));
      acc1 = fmaf(x1.x,w.x, fmaf(x1.y,w.y, fmaf(x1.z,w.z, fmaf(x1.w,w.w, acc1))));
    }
    if (t < 127){
      int sposn = dir ? 126 - t : t+1;
      #pragma unroll
      for (int i=0;i<2;i++)
        nxt[i] = gx[(size_t)(sposn*128 + b0 + ng*2 + i)*1024 + gt*128 + grow];
    }
    // same-wave gate exchange (lgkmcnt-ordered, no barrier)
    gbuf[(wave*16 + gl)*10 + ng*2+0] = acc0;
    gbuf[(wave*16 + gl)*10 + ng*2+1] = acc1;
    if (l < 32){
      float g_i = gbuf[(wave*16 + ul*4+0)*10 + nn];
      float g_f = gbuf[(wave*16 + ul*4+1)*10 + nn];
      float g_g = gbuf[(wave*16 + ul*4+2)*10 + nn];
      float g_o = gbuf[(wave*16 + ul*4+3)*10 + nn];
      creg = sigm(g_f)*creg + sigm(g_i)*tanhf(g_g);
      float h = sigm(g_o)*tanhf(creg);
      float* hn = ((t&1)==0) ? hB : hA;
      __hip_atomic_store(&hn[(size_t)(dir*128 + b0 + nn)*256 + au], h,
                         __ATOMIC_RELAXED, __HIP_MEMORY_SCOPE_AGENT);
      hs[(size_t)(spos*128 + b0 + nn)*256 + au] = h;
    }
    __syncthreads();   // drains vmcnt(0): all h stores acked at coherence point
    if (tid==0){
      atomicAdd(ctr, 1u);
      unsigned int target = 8u*(unsigned)(t+1);
      while (__hip_atomic_load(ctr, __ATOMIC_RELAXED, __HIP_MEMORY_SCOPE_AGENT) < target)
        __builtin_amdgcn_s_sleep(2);
    }
    __syncthreads();
    if (t < 127){
      const float* hc = ((t&1)==0) ? hB : hA;
      int row = tid >> 6, col4 = (tid & 63) * 4;
      const float* p = &hc[(size_t)(dir*128 + b0 + row)*256 + col4];
      f32x4 v;
      asm volatile("global_load_dwordx4 %0, %1, off sc0 sc1"
                   : "=v"(v) : "v"(p) : "memory");
      asm volatile("s_waitcnt vmcnt(0)" ::: "memory");
      __builtin_amdgcn_sched_barrier(0);
      *(f32x4*)&hstage[row*264 + col4] = v;
      __syncthreads();
    }
  }
}

// ---------------------------------------------------------------------------
// feats[b*128+s][k] = tag_b[k] + [hsf|hsb|chvec|fv] . tag_W[k]  (K=704, 2 passes)
__global__ __launch_bounds__(256) void k_feats(
  const float* __restrict__ hsf, const float* __restrict__ hsb,
  const float* __restrict__ chvec, const float* __restrict__ fvb,
  const float* __restrict__ tagW, const float* __restrict__ tagb,
  float* __restrict__ feats)
{
  __shared__ __align__(16) float Wt[27*352];
  int tid=threadIdx.x, bid=blockIdx.x;
  int wave=__builtin_amdgcn_readfirstlane((int)(tid>>6));
  int l=tid&63;
  int r0=bid*32+wave*8;
  bool act = (l < 27);
  float acc[8];
  #pragma unroll
  for (int i=0;i<8;i++) acc[i] = act ? tagb[l] : 0.f;
  const float* hfr[8]; const float* hbr[8]; const float* cr[8]; const float* fr[8];
  #pragma unroll
  for (int i=0;i<8;i++){
    int r=r0+i; int b=r>>7, sw=r&127;
    hfr[i]=hsf + (size_t)(sw*128+b)*256;
    hbr[i]=hsb + (size_t)(sw*128+b)*256;
    cr[i]=chvec + (size_t)r*64;
    fr[i]=fvb + (size_t)r*128;
  }
  for (int i=tid;i<27*88;i+=256){
    int rr=i/88, k4=i%88;
    *(float4*)&Wt[(rr*352+k4*4)^((rr&7)<<2)] = *(const float4*)(tagW + rr*704 + k4*4);
  }
  __syncthreads();
  if (act){
    for (int k4=0;k4<64;k4++){
      float4 w=*(const float4*)&Wt[(l*352+k4*4)^((l&7)<<2)];
      #pragma unroll
      for (int i=0;i<8;i++){
        const float4 x=*(const float4*)(hfr[i]+k4*4);
        acc[i]=fmaf(x.x,w.x,fmaf(x.y,w.y,fmaf(x.z,w.z,fmaf(x.w,w.w,acc[i]))));
      }
    }
    for (int k4=64;k4<88;k4++){
      float4 w=*(const float4*)&Wt[(l*352+k4*4)^((l&7)<<2)];
      #pragma unroll
      for (int i=0;i<8;i++){
        const float4 x=*(const float4*)(hbr[i]+(k4-64)*4);
        acc[i]=fmaf(x.x,w.x,fmaf(x.y,w.y,fmaf(x.z,w.z,fmaf(x.w,w.w,acc[i]))));
      }
    }
  }
  __syncthreads();
  for (int i=tid;i<27*88;i+=256){
    int rr=i/88, k4=i%88;
    *(float4*)&Wt[(rr*352+k4*4)^((rr&7)<<2)] = *(const float4*)(tagW + rr*704 + 352 + k4*4);
  }
  __syncthreads();
  if (act){
    for (int k4=0;k4<40;k4++){
      float4 w=*(const float4*)&Wt[(l*352+k4*4)^((l&7)<<2)];
      #pragma unroll
      for (int i=0;i<8;i++){
        const float4 x=*(const float4*)(hbr[i]+96+k4*4);
        acc[i]=fmaf(x.x,w.x,fmaf(x.y,w.y,fmaf(x.z,w.z,fmaf(x.w,w.w,acc[i]))));
      }
    }
    for (int k4=40;k4<56;k4++){
      float4 w=*(const float4*)&Wt[(l*352+k4*4)^((l&7)<<2)];
      #pragma unroll
      for (int i=0;i<8;i++){
        const float4 x=*(const float4*)(cr[i]+(k4-40)*4);
        acc[i]=fmaf(x.x,w.x,fmaf(x.y,w.y,fmaf(x.z,w.z,fmaf(x.w,w.w,acc[i]))));
      }
    }
    for (int k4=56;k4<88;k4++){
      float4 w=*(const float4*)&Wt[(l*352+k4*4)^((l&7)<<2)];
      #pragma unroll
      for (int i=0;i<8;i++){
        const float4 x=*(const float4*)(fr[i]+(k4-56)*4);
        acc[i]=fmaf(x.x,w.x,fmaf(x.y,w.y,fmaf(x.z,w.z,fmaf(x.w,w.w,acc[i]))));
      }
    }
    #pragma unroll
    for (int i=0;i<8;i++) feats[(size_t)(r0+i)*27 + l] = acc[i];
  }
}

// ---------------------------------------------------------------------------
__global__ __launch_bounds__(256) void k_argmax(const float* __restrict__ feats,
                                                float* __restrict__ out)
{
  int r = blockIdx.x*256 + threadIdx.x;
  const float* f = feats + (size_t)r*27;
  float best = f[0]; int bi = 0;
  #pragma unroll
  for (int j=1;j<27;j++){ float v=f[j]; if (v>best){best=v;bi=j;} }
  out[r] = (float)bi;
}

// ---------------------------------------------------------------------------
__global__ __launch_bounds__(64) void k_viterbi(
  const float* __restrict__ feats, const int* __restrict__ mask,
  const float* __restrict__ trans, float* __restrict__ out)
{
  __shared__ float tr[729];
  __shared__ unsigned char bp[127][27];
  __shared__ int tags[128];
  int b = blockIdx.x, l = threadIdx.x;
  for (int i=l;i<729;i+=64) tr[i]=trans[i];
  __syncthreads();
  int ll = (l<27) ? l : 0;
  float trc[27];
  #pragma unroll
  for (int i=0;i<27;i++) trc[i]=tr[i*27+ll];
  const float* fb_ = feats + (size_t)b*128*27;
  float score = fb_[ll] + tr[25*27 + ll];
  for (int t=1;t<128;t++){
    float best=-3.0e38f; int bi=0;
    #pragma unroll 1
    for (int i=0;i<27;i++){
      float si = __shfl(score, i, 64);
      float cand = si + trc[i];
      if (cand > best){ best=cand; bi=i; }
    }
    int m = mask[b*128 + t];
    float ns = best + fb_[t*27 + ll];
    if (m) score = ns;
    int bpv = m ? bi : ll;
    if (l < 27) bp[t-1][l] = (unsigned char)bpv;
  }
  float fin = score + tr[ll*27 + 26];
  if (l >= 27) fin = -3.0e38f;
  float bestf=-3.0e38f; int bt=0;
  #pragma unroll 1
  for (int i=0;i<27;i++){
    float v=__shfl(fin, i, 64);
    if (v > bestf){ bestf=v; bt=i; }
  }
  if (l==0){
    out[b]=bestf;
    int tg=bt; tags[127]=tg;
    for (int t=126;t>=0;t--){ tg = bp[t][tg]; tags[t]=tg; }
  }
  __syncthreads();
  float* op = out + 128 + b*128;
  for (int t=l;t<128;t+=64) op[t]=(float)tags[t];
}

// ---------------------------------------------------------------------------
extern "C" void kernel_launch(void* const* d_in, const int* in_sizes, int n_in,
                              void* d_out, int out_size, void* d_ws, size_t ws_size,
                              hipStream_t stream)
{
  (void)in_sizes; (void)n_in; (void)out_size; (void)ws_size;
  const int*   words2ix = (const int*)d_in[0];
  const int*   chars2ix = (const int*)d_in[1];
  const float* features = (const float*)d_in[2];
  const int*   amask    = (const int*)d_in[3];
  const float* word_emb = (const float*)d_in[4];
  const float* char_emb = (const float*)d_in[5];
  const float* cWih_f=(const float*)d_in[6],  *cWhh_f=(const float*)d_in[7];
  const float* cbih_f=(const float*)d_in[8],  *cbhh_f=(const float*)d_in[9];
  const float* cWih_b=(const float*)d_in[10], *cWhh_b=(const float*)d_in[11];
  const float* cbih_b=(const float*)d_in[12], *cbhh_b=(const float*)d_in[13];
  const float* coW=(const float*)d_in[14], *cob=(const float*)d_in[15];
  const float* fW =(const float*)d_in[16], *fb =(const float*)d_in[17];
  const float* lWih_f=(const float*)d_in[18], *lWhh_f=(const float*)d_in[19];
  const float* lbih_f=(const float*)d_in[20], *lbhh_f=(const float*)d_in[21];
  const float* lWih_b=(const float*)d_in[22], *lWhh_b=(const float*)d_in[23];
  const float* lbih_b=(const float*)d_in[24], *lbhh_b=(const float*)d_in[25];
  const float* tagW=(const float*)d_in[26], *tagb=(const float*)d_in[27];
  const float* trans=(const float*)d_in[28];
  float* out = (float*)d_out;

  float* p = (float*)d_ws;
  float* chvec = p; p += 16384*64;
  float* fvb   = p; p += 16384*128;
  float* gxf   = p; p += (size_t)16384*1024;
  float* gxb   = p; p += (size_t)16384*1024;
  float* chh   = p; p += 2*16384*64;
  float* tab   = p; p += 2*500*256;
  float* hA    = p; p += 2*128*256;
  float* hB    = p; p += 2*128*256;
  float* hsf   = p; p += (size_t)128*128*256;
  float* hsb   = p; p += (size_t)128*128*256;
  float* feats = p; p += 16384*27;
  unsigned int* cnt = (unsigned int*)p;   // 32 groups x 64 uints (padded)

  hipMemsetAsync(cnt, 0, 32*64*sizeof(unsigned int), stream);

  k_gxc<<<1000,256,0,stream>>>(char_emb, cWih_f,cbih_f,cbhh_f, cWih_b,cbih_b,cbhh_b, tab);
  k_fv<<<8192,256,0,stream>>>(features, fW, fb, fvb);
  k_char<<<4096,256,0,stream>>>(chars2ix, cWhh_f, cWhh_b, tab, chh);
  k_chvec<<<256,256,0,stream>>>(chh, coW, cob, chvec);
  k_gxall<<<2048,256,0,stream>>>(words2ix, word_emb, chvec, fvb,
      lWih_f,lbih_f,lbhh_f, lWih_b,lbih_b,lbhh_b, gxf, gxb);
  k_sent<<<256,512,0,stream>>>(gxf, gxb, lWhh_f, lWhh_b, hA, hB, hsf, hsb, cnt);
  k_feats<<<512,256,0,stream>>>(hsf, hsb, chvec, fvb, tagW, tagb, feats);
  k_argmax<<<64,256,0,stream>>>(feats, out + 128 + 16384);
  k_viterbi<<<128,64,0,stream>>>(feats, amask, trans, out);
}